// Round 13
// baseline (201.604 us; speedup 1.0000x reference)
//
#include <hip/hip_runtime.h>
#include <hip/hip_bf16.h>

// Problem constants (fixed by the reference)
#define CS     128
#define EDIM   256
#define NBATCH 2
#define TLEN   8192
#define NCHUNK 64
#define LEXT   1024
#define KSEL   7

typedef __attribute__((ext_vector_type(8))) short   short8;   // 8 bf16 = 4 VGPR (MFMA A/B frag)
typedef __attribute__((ext_vector_type(4))) float   floatx4;  // MFMA C/D frag

__device__ inline short bf16_of(float f) {
    __hip_bfloat16 h = __float2bfloat16(f);
    return *(short*)&h;
}
__device__ inline float f_of_bf16(short s) {
    __hip_bfloat16 h = *(__hip_bfloat16*)&s;
    return __bfloat162float(h);
}

// async global->LDS, 16B per lane; LDS dest = wave-uniform base + lane*16
__device__ inline void gl_lds16(const void* g, void* l) {
    __builtin_amdgcn_global_load_lds(
        (const __attribute__((address_space(1))) unsigned int*)g,
        (__attribute__((address_space(3))) unsigned int*)l, 16, 0, 0);
}

// raw barrier (no compiler vmcnt(0) drain) — counted vmcnt crosses it
#define RAW_BAR() asm volatile("s_barrier" ::: "memory")

// ---------------------------------------------------------------------------
// Fused prep v2 (round-10 measured-best, verbatim): r1 layouts (cn row-major,
// xt_hi [b][e][T], dp_hi [c][L]) with 16B short8 stores. 264 blocks x 256 thr.
// ---------------------------------------------------------------------------
__global__ __launch_bounds__(256) void prep_kernel(const float* __restrict__ x,
                                                   const float* __restrict__ dp,
                                                   short* __restrict__ cn_hi,
                                                   short* __restrict__ cn_lo,
                                                   short* __restrict__ xt_hi,
                                                   short* __restrict__ dp_hi) {
    const int bx = blockIdx.x;
    if (bx >= 256) {            // dp conversion: 8 blocks x 256 thr, short8 stores
        int t = (bx - 256) * 256 + threadIdx.x;
#pragma unroll
        for (int u = 0; u < 8; ++u) {
            int idx = (t * 16 + u * 2) * 4;
            float4 v0 = *(const float4*)(dp + idx);
            float4 v1 = *(const float4*)(dp + idx + 4);
            short8 sv;
            sv[0] = bf16_of(v0.x); sv[1] = bf16_of(v0.y);
            sv[2] = bf16_of(v0.z); sv[3] = bf16_of(v0.w);
            sv[4] = bf16_of(v1.x); sv[5] = bf16_of(v1.y);
            sv[6] = bf16_of(v1.z); sv[7] = bf16_of(v1.w);
            *(short8*)(dp_hi + idx) = sv;
        }
        return;
    }

    __shared__ float tile[64 * 257];   // [t-row][e], pitch 257
    const int b = bx >> 7, t0 = (bx & 127) * 64;
    const int tid = threadIdx.x;
    const int r = tid >> 2, q = tid & 3;   // row r (0..63), quarter q (64 elems)

    const float* src = x + ((size_t)(b * TLEN + t0 + r)) * EDIM + q * 64;
    float* trow = &tile[r * 257 + q * 64];
    float s = 0.f;
#pragma unroll
    for (int u = 0; u < 16; ++u) {
        float4 v = *(const float4*)(src + u * 4);
        s += v.x * v.x + v.y * v.y + v.z * v.z + v.w * v.w;
        trow[u * 4 + 0] = v.x; trow[u * 4 + 1] = v.y;
        trow[u * 4 + 2] = v.z; trow[u * 4 + 3] = v.w;
    }
    s += __shfl_xor(s, 1);
    s += __shfl_xor(s, 2);
    const float rn = 1.0f / (sqrtf(s) + 1e-6f);

    short* ch = cn_hi + ((size_t)(b * TLEN + t0 + r)) * EDIM + q * 64;
    short* cl = cn_lo + ((size_t)(b * TLEN + t0 + r)) * EDIM + q * 64;
#pragma unroll
    for (int u = 0; u < 8; ++u) {
        short8 hv, lv;
#pragma unroll
        for (int k2 = 0; k2 < 8; ++k2) {
            float c = trow[u * 8 + k2] * rn;
            short hh = bf16_of(c);
            hv[k2] = hh;
            lv[k2] = bf16_of(c - f_of_bf16(hh));
        }
        *(short8*)(ch + u * 8) = hv;
        *(short8*)(cl + u * 8) = lv;
    }
    __syncthreads();

    // xt_hi write ([b][e][T]): thread (g32 = tid>>3, tq8 = tid&7)
    const int g32 = tid >> 3, tq8 = tid & 7;
#pragma unroll
    for (int it = 0; it < 8; ++it) {
        int e = g32 + it * 32;
        short8 hv;
#pragma unroll
        for (int g = 0; g < 8; ++g)
            hv[g] = bf16_of(tile[(tq8 * 8 + g) * 257 + e]);
        *(short8*)(xt_hi + ((size_t)(b * EDIM + e)) * TLEN + t0 + tq8 * 8) = hv;
    }
}

// ---------------------------------------------------------------------------
// Stage B (r1 proven version + T1 XCD-chunked blockIdx swizzle): split-bf16
// 16x16x32 MFMA cosine scores, XOR bank swizzle, double-buffered LDS (64 KB),
// counted vmcnt(8) across raw barriers, setprio.
// T1: grid.x = 2016 = 8 x 252; p = (p0&7)*252 + (p0>>3) gives each XCD a
// CONTIGUOUS p-range -> consecutive p share chunk i, whose 128 KB hi+lo
// tiles then stay hot in that XCD's 4 MB L2 (staging was ~85% L3-served:
// 1.03 GB staged vs 182 MB FETCH). Numerics bit-identical (pure remap).
// ---------------------------------------------------------------------------
__global__ __launch_bounds__(256) void scores_mfma(const short* __restrict__ cn_hi,
                                                   const short* __restrict__ cn_lo,
                                                   float* __restrict__ scores) {
    __shared__ short tiles[2][4][4096];         // [buf][tile][..] 64 KB exactly
    double* red2   = (double*)&tiles[0][0][0];  // alias (epilogue only)
    float*  redbuf = (float*)&tiles[0][0][8];   // alias, bytes [16, 1040)

    const int p0 = blockIdx.x, b = blockIdx.y;
    const int p = (p0 & 7) * 252 + (p0 >> 3);   // T1 swizzle (2016 % 8 == 0)
    int i = (int)((1.0f + sqrtf(1.0f + 8.0f * (float)p)) * 0.5f);
    while (i * (i - 1) / 2 > p) --i;
    while (i * (i + 1) / 2 <= p) ++i;
    const int j = p - i * (i - 1) / 2;

    const int tid  = threadIdx.x;
    const int w    = tid >> 6, lane = tid & 63;
    const int wr   = w >> 1, wc = w & 1;
    const int quad = lane >> 4, l15 = lane & 15;

    const short* sarr  = (w & 1) ? cn_lo : cn_hi;
    const size_t sbase = ((size_t)b * TLEN + ((w >> 1) ? j : i) * CS) * EDIM;
    const int rr  = lane >> 2;
    const int c16 = (lane & 3) * 8;
    const int csw = c16 ^ (((rr >> 1) & 3) * 8);       // staging swizzle
    const int q8  = (quad ^ ((l15 >> 1) & 3)) * 8;     // frag-read swizzle

    // each wave stages its own tile (w: A_hi / A_lo / B_hi / B_lo), 8x1KB
    auto stage = [&](int ks, int bf) {
        const short* gsrc = sarr + sbase + ks * 32 + csw;
        short* ldst = &tiles[bf][w][0];
#pragma unroll
        for (int t = 0; t < 8; ++t)
            gl_lds16(gsrc + (size_t)(16 * t + rr) * EDIM, ldst + t * 512);
    };

    floatx4 acc[4][4];
#pragma unroll
    for (int rt = 0; rt < 4; ++rt)
#pragma unroll
        for (int ct = 0; ct < 4; ++ct) acc[rt][ct] = (floatx4){0.f, 0.f, 0.f, 0.f};

    stage(0, 0);
    int buf = 0;
    for (int ks = 0; ks < 8; ++ks) {
        if (ks < 7) {
            stage(ks + 1, buf ^ 1);                       // 8 loads in flight
            asm volatile("s_waitcnt vmcnt(8)" ::: "memory");  // old 8 landed
        } else {
            asm volatile("s_waitcnt vmcnt(0)" ::: "memory");
        }
        RAW_BAR();   // all waves' current-buf loads have landed

        short8 bh[4], bl[4];
#pragma unroll
        for (int ct = 0; ct < 4; ++ct) {
            int r = wc * 64 + ct * 16 + l15;
            bh[ct] = *(const short8*)&tiles[buf][2][r * 32 + q8];
            bl[ct] = *(const short8*)&tiles[buf][3][r * 32 + q8];
        }
        __builtin_amdgcn_s_setprio(1);
#pragma unroll
        for (int rt = 0; rt < 4; ++rt) {
            int r = wr * 64 + rt * 16 + l15;
            short8 ah = *(const short8*)&tiles[buf][0][r * 32 + q8];
            short8 al = *(const short8*)&tiles[buf][1][r * 32 + q8];
#pragma unroll
            for (int ct = 0; ct < 4; ++ct) {
                acc[rt][ct] = __builtin_amdgcn_mfma_f32_16x16x32_bf16(ah, bh[ct], acc[rt][ct], 0, 0, 0);
                acc[rt][ct] = __builtin_amdgcn_mfma_f32_16x16x32_bf16(ah, bl[ct], acc[rt][ct], 0, 0, 0);
                acc[rt][ct] = __builtin_amdgcn_mfma_f32_16x16x32_bf16(al, bh[ct], acc[rt][ct], 0, 0, 0);
            }
        }
        __builtin_amdgcn_s_setprio(0);
        RAW_BAR();   // all waves done reading buf before next stage overwrites
        buf ^= 1;
    }

#pragma unroll
    for (int rt = 0; rt < 4; ++rt) {
        float m[4];
#pragma unroll
        for (int reg = 0; reg < 4; ++reg) {
            float mm = acc[rt][0][reg];
#pragma unroll
            for (int ct = 1; ct < 4; ++ct) mm = fmaxf(mm, acc[rt][ct][reg]);
            m[reg] = mm;
        }
#pragma unroll
        for (int off = 1; off < 16; off <<= 1)
#pragma unroll
            for (int reg = 0; reg < 4; ++reg) m[reg] = fmaxf(m[reg], __shfl_xor(m[reg], off));
        if (l15 == 0) {
#pragma unroll
            for (int reg = 0; reg < 4; ++reg)
                redbuf[wc * 128 + wr * 64 + rt * 16 + quad * 4 + reg] = m[reg];
        }
    }
    __syncthreads();

    double part = 0.0;
    if (tid < 128) part = (double)fmaxf(redbuf[tid], redbuf[128 + tid]);
#pragma unroll
    for (int off = 1; off < 64; off <<= 1) part += __shfl_xor(part, off);
    if (lane == 0 && w < 2) red2[w] = part;
    __syncthreads();
    if (tid == 0) scores[(b * NCHUNK + i) * NCHUNK + j] = (float)(red2[0] + red2[1]);
}

// ---------------------------------------------------------------------------
// Stage D v7 (measured best — 199.3 us total in r10; v10 stage-early was
// null/noise-worse in r12): out = dp @ ext + chunk, K=64 steps (2 k32
// sub-slices each), 3 LDS buffers, prefetch depth 2, ONE raw barrier per
// step, counted per-wave vmcnt. dph = [c][L], xth = [b][e][T]. Verbatim.
// ---------------------------------------------------------------------------
__global__ __launch_bounds__(256) void out_mfma(const float* __restrict__ x,
                                                const short* __restrict__ dph,
                                                const short* __restrict__ xth,
                                                const float* __restrict__ scores,
                                                float* __restrict__ out) {
    __shared__ short As[3][2][128 * 32];   // [buf][sub][c][k]  48 KB
    __shared__ short Bs[3][2][64 * 32];    // [buf][sub][e][k]  24 KB
    __shared__ int   slist[8], sslot[8], snum;
    __shared__ float swei[8];

    const int eq = blockIdx.x, n = blockIdx.y, b = blockIdx.z;
    const int e0 = eq * 64;
    const int tid  = threadIdx.x;
    const int w    = tid >> 6, lane = tid & 63;
    const int wr   = w >> 1, wc = w & 1;
    const int quad = lane >> 4, l15 = lane & 15;
    const int rr   = lane >> 2;
    const int c16  = (lane & 3) * 8;
    const int csw  = c16 ^ (((rr >> 1) & 3) * 8);
    const int q8   = (quad ^ ((l15 >> 1) & 3)) * 8;

    // ---- inlined top-7 (wave 0): candidates j in [0, n) ----
    if (w == 0) {
        const float* srow = scores + (b * NCHUNK + n) * NCHUNK;
        const int nsel = n < KSEL ? n : KSEL;
        float v = (lane < n) ? srow[lane] : -3.0e38f;
        float vals[KSEL];
        int   idxs[KSEL];
        for (int s2 = 0; s2 < nsel; ++s2) {
            float bv = v; int bi = lane;
#pragma unroll
            for (int off = 1; off < 64; off <<= 1) {
                float ov = __shfl_xor(bv, off);
                int   oi = __shfl_xor(bi, off);
                if (ov > bv || (ov == bv && oi < bi)) { bv = ov; bi = oi; }
            }
            vals[s2] = bv; idxs[s2] = bi;
            if (lane == bi) v = -3.0e38f;
        }
        if (lane == 0) {
            float vmin = (nsel > 0) ? vals[nsel - 1] : 0.0f;
            float inv  = 1.0f / (vmin + 1e-6f);
            int shift  = KSEL - nsel;
            int c = 0;
            for (int s2 = 0; s2 < 8; ++s2) {
                int jj; float ww;
                if (s2 < KSEL) {
                    int tt = s2 - shift;
                    if (tt >= 0) { jj = idxs[tt]; ww = vals[tt] * inv; }
                    else         { jj = -1;       ww = 0.0f; }
                } else { jj = n; ww = 1.0f; }
                if (jj >= 0) { slist[c] = jj; sslot[c] = s2; swei[c] = ww; ++c; }
            }
            snum = c;
        }
    }
    __syncthreads();
    const int NT = snum * 2;   // K=64 steps (2 k32 sub-slices per step)

    // stage step st into buffer b3: waves 0-1 stage As (8 loads), 2-3 Bs (4)
    auto stage = [&](int st, int b3) {
        int sv = st >> 1, kh = st & 1;
        if (w < 2) {
#pragma unroll
            for (int sub = 0; sub < 2; ++sub) {
                const short* gsrc = dph + (size_t)(sslot[sv] * 128 + (kh * 2 + sub) * 32) + csw;
#pragma unroll
                for (int t = 0; t < 4; ++t)
                    gl_lds16(gsrc + (size_t)(w * 64 + t * 16 + rr) * LEXT,
                             &As[b3][sub][(w * 64 + t * 16) * 32]);
            }
        } else {
#pragma unroll
            for (int sub = 0; sub < 2; ++sub) {
                const short* gsrc = xth + ((size_t)(b * EDIM + e0)) * TLEN
                                    + (size_t)(slist[sv] * CS + (kh * 2 + sub) * 32) + csw;
#pragma unroll
                for (int t = 0; t < 2; ++t)
                    gl_lds16(gsrc + (size_t)((w - 2) * 32 + t * 16 + rr) * TLEN,
                             &Bs[b3][sub][((w - 2) * 32 + t * 16) * 32]);
            }
        }
    };

    floatx4 accT[4][2], accP[4][2];
#pragma unroll
    for (int rt = 0; rt < 4; ++rt)
#pragma unroll
        for (int ct = 0; ct < 2; ++ct) accT[rt][ct] = (floatx4){0.f, 0.f, 0.f, 0.f};

    stage(0, 0);
    if (NT > 1) stage(1, 1);
    // ensure stage 0 landed (allow stage 1's loads to remain in flight)
    if (w < 2) asm volatile("s_waitcnt vmcnt(8)" ::: "memory");
    else       asm volatile("s_waitcnt vmcnt(4)" ::: "memory");

    int cur = 0;
    for (int st = 0; st < NT; ++st) {
        RAW_BAR();   // all waves: buf 'cur' landed, and compute(st-1) finished

        if ((st & 1) == 0) {
#pragma unroll
            for (int rt = 0; rt < 4; ++rt)
#pragma unroll
                for (int ct = 0; ct < 2; ++ct) accP[rt][ct] = (floatx4){0.f, 0.f, 0.f, 0.f};
        }

#pragma unroll
        for (int sub = 0; sub < 2; ++sub) {
            short8 bh[2];
#pragma unroll
            for (int ct = 0; ct < 2; ++ct) {
                int e = wc * 32 + ct * 16 + l15;
                bh[ct] = *(const short8*)&Bs[cur][sub][e * 32 + q8];
            }
            __builtin_amdgcn_s_setprio(1);
#pragma unroll
            for (int rt = 0; rt < 4; ++rt) {
                int r = wr * 64 + rt * 16 + l15;
                short8 ah = *(const short8*)&As[cur][sub][r * 32 + q8];
#pragma unroll
                for (int ct = 0; ct < 2; ++ct)
                    accP[rt][ct] = __builtin_amdgcn_mfma_f32_16x16x32_bf16(ah, bh[ct], accP[rt][ct], 0, 0, 0);
            }
            __builtin_amdgcn_s_setprio(0);
        }

        if ((st & 1) == 1) {
            float wcur = swei[st >> 1];
#pragma unroll
            for (int rt = 0; rt < 4; ++rt)
#pragma unroll
                for (int ct = 0; ct < 2; ++ct)
#pragma unroll
                    for (int reg = 0; reg < 4; ++reg)
                        accT[rt][ct][reg] += wcur * accP[rt][ct][reg];
        }

        if (st + 2 < NT) {
            int tgt = cur ? cur - 1 : 2;        // (cur+2)%3
            stage(st + 2, tgt);
            if (w < 2) asm volatile("s_waitcnt vmcnt(8)" ::: "memory");
            else       asm volatile("s_waitcnt vmcnt(4)" ::: "memory");
        } else if (st + 1 < NT) {
            asm volatile("s_waitcnt vmcnt(0)" ::: "memory");
        }
        cur = (cur == 2) ? 0 : cur + 1;
    }

#pragma unroll
    for (int rt = 0; rt < 4; ++rt)
#pragma unroll
        for (int ct = 0; ct < 2; ++ct) {
#pragma unroll
            for (int reg = 0; reg < 4; ++reg) {
                int row = wr * 64 + rt * 16 + quad * 4 + reg;
                int col = wc * 32 + ct * 16 + l15;
                size_t o = ((size_t)(b * TLEN + n * CS + row)) * EDIM + e0 + col;
                out[o] = accT[rt][ct][reg] + x[o];
            }
        }
}

// ---------------------------------------------------------------------------
extern "C" void kernel_launch(void* const* d_in, const int* in_sizes, int n_in,
                              void* d_out, int out_size, void* d_ws, size_t ws_size,
                              hipStream_t stream) {
    const float* x  = (const float*)d_in[0];   // [2, 8192, 256] fp32
    const float* dp = (const float*)d_in[1];   // [128, 1024] fp32
    float* out = (float*)d_out;

    char* ws = (char*)d_ws;
    short* cn_hi  = (short*)(ws);                       // 8 MB
    short* cn_lo  = (short*)(ws + (8u << 20));          // 8 MB
    short* xt_hi  = (short*)(ws + (16u << 20));         // 8 MB  [b][e][T]
    short* dp_hi  = (short*)(ws + (24u << 20));         // 256 KB [c][L]
    float* scores = (float*)(ws + (25u << 20));         // 32 KB

    prep_kernel <<<dim3(264), 256, 0, stream>>>(x, dp, cn_hi, cn_lo, xt_hi, dp_hi);
    scores_mfma <<<dim3(NCHUNK * (NCHUNK - 1) / 2, NBATCH), 256, 0, stream>>>(cn_hi, cn_lo, scores);
    out_mfma    <<<dim3(4, NCHUNK, NBATCH), 256, 0, stream>>>(x, dp_hi, xt_hi, scores, out);
}

// Round 14
// 198.271 us; speedup vs baseline: 1.0168x; 1.0168x over previous
//
#include <hip/hip_runtime.h>
#include <hip/hip_bf16.h>

// Problem constants (fixed by the reference)
#define CS     128
#define EDIM   256
#define NBATCH 2
#define TLEN   8192
#define NCHUNK 64
#define LEXT   1024
#define KSEL   7

typedef __attribute__((ext_vector_type(8))) short   short8;   // 8 bf16 = 4 VGPR (MFMA A/B frag)
typedef __attribute__((ext_vector_type(4))) float   floatx4;  // MFMA C/D frag

__device__ inline short bf16_of(float f) {
    __hip_bfloat16 h = __float2bfloat16(f);
    return *(short*)&h;
}
__device__ inline float f_of_bf16(short s) {
    __hip_bfloat16 h = *(__hip_bfloat16*)&s;
    return __bfloat162float(h);
}

// async global->LDS, 16B per lane; LDS dest = wave-uniform base + lane*16
__device__ inline void gl_lds16(const void* g, void* l) {
    __builtin_amdgcn_global_load_lds(
        (const __attribute__((address_space(1))) unsigned int*)g,
        (__attribute__((address_space(3))) unsigned int*)l, 16, 0, 0);
}

// raw barrier (no compiler vmcnt(0) drain) — counted vmcnt crosses it
#define RAW_BAR() asm volatile("s_barrier" ::: "memory")

// ---------------------------------------------------------------------------
// Fused prep v2 (round-10 measured-best, verbatim): r1 layouts (cn row-major,
// xt_hi [b][e][T], dp_hi [c][L]) with 16B short8 stores. 264 blocks x 256 thr.
// ---------------------------------------------------------------------------
__global__ __launch_bounds__(256) void prep_kernel(const float* __restrict__ x,
                                                   const float* __restrict__ dp,
                                                   short* __restrict__ cn_hi,
                                                   short* __restrict__ cn_lo,
                                                   short* __restrict__ xt_hi,
                                                   short* __restrict__ dp_hi) {
    const int bx = blockIdx.x;
    if (bx >= 256) {            // dp conversion: 8 blocks x 256 thr, short8 stores
        int t = (bx - 256) * 256 + threadIdx.x;
#pragma unroll
        for (int u = 0; u < 8; ++u) {
            int idx = (t * 16 + u * 2) * 4;
            float4 v0 = *(const float4*)(dp + idx);
            float4 v1 = *(const float4*)(dp + idx + 4);
            short8 sv;
            sv[0] = bf16_of(v0.x); sv[1] = bf16_of(v0.y);
            sv[2] = bf16_of(v0.z); sv[3] = bf16_of(v0.w);
            sv[4] = bf16_of(v1.x); sv[5] = bf16_of(v1.y);
            sv[6] = bf16_of(v1.z); sv[7] = bf16_of(v1.w);
            *(short8*)(dp_hi + idx) = sv;
        }
        return;
    }

    __shared__ float tile[64 * 257];   // [t-row][e], pitch 257
    const int b = bx >> 7, t0 = (bx & 127) * 64;
    const int tid = threadIdx.x;
    const int r = tid >> 2, q = tid & 3;   // row r (0..63), quarter q (64 elems)

    const float* src = x + ((size_t)(b * TLEN + t0 + r)) * EDIM + q * 64;
    float* trow = &tile[r * 257 + q * 64];
    float s = 0.f;
#pragma unroll
    for (int u = 0; u < 16; ++u) {
        float4 v = *(const float4*)(src + u * 4);
        s += v.x * v.x + v.y * v.y + v.z * v.z + v.w * v.w;
        trow[u * 4 + 0] = v.x; trow[u * 4 + 1] = v.y;
        trow[u * 4 + 2] = v.z; trow[u * 4 + 3] = v.w;
    }
    s += __shfl_xor(s, 1);
    s += __shfl_xor(s, 2);
    const float rn = 1.0f / (sqrtf(s) + 1e-6f);

    short* ch = cn_hi + ((size_t)(b * TLEN + t0 + r)) * EDIM + q * 64;
    short* cl = cn_lo + ((size_t)(b * TLEN + t0 + r)) * EDIM + q * 64;
#pragma unroll
    for (int u = 0; u < 8; ++u) {
        short8 hv, lv;
#pragma unroll
        for (int k2 = 0; k2 < 8; ++k2) {
            float c = trow[u * 8 + k2] * rn;
            short hh = bf16_of(c);
            hv[k2] = hh;
            lv[k2] = bf16_of(c - f_of_bf16(hh));
        }
        *(short8*)(ch + u * 8) = hv;
        *(short8*)(cl + u * 8) = lv;
    }
    __syncthreads();

    // xt_hi write ([b][e][T]): thread (g32 = tid>>3, tq8 = tid&7)
    const int g32 = tid >> 3, tq8 = tid & 7;
#pragma unroll
    for (int it = 0; it < 8; ++it) {
        int e = g32 + it * 32;
        short8 hv;
#pragma unroll
        for (int g = 0; g < 8; ++g)
            hv[g] = bf16_of(tile[(tq8 * 8 + g) * 257 + e]);
        *(short8*)(xt_hi + ((size_t)(b * EDIM + e)) * TLEN + t0 + tq8 * 8) = hv;
    }
}

// ---------------------------------------------------------------------------
// Stage B (r1 proven version, verbatim — measured 110.2-112.5 us x6,
// MfmaUtil ~40%, conflicts 0; occupancy x2, traffic /2 x2, 32x32 shape,
// staging layouts, and T1 XCD swizzle all failed to beat it): split-bf16
// 16x16x32 MFMA cosine scores, XOR bank swizzle, double-buffered LDS
// (64 KB), counted vmcnt(8) across raw barriers, setprio.
// ---------------------------------------------------------------------------
__global__ __launch_bounds__(256) void scores_mfma(const short* __restrict__ cn_hi,
                                                   const short* __restrict__ cn_lo,
                                                   float* __restrict__ scores) {
    __shared__ short tiles[2][4][4096];         // [buf][tile][..] 64 KB exactly
    double* red2   = (double*)&tiles[0][0][0];  // alias (epilogue only)
    float*  redbuf = (float*)&tiles[0][0][8];   // alias, bytes [16, 1040)

    const int p = blockIdx.x, b = blockIdx.y;
    int i = (int)((1.0f + sqrtf(1.0f + 8.0f * (float)p)) * 0.5f);
    while (i * (i - 1) / 2 > p) --i;
    while (i * (i + 1) / 2 <= p) ++i;
    const int j = p - i * (i - 1) / 2;

    const int tid  = threadIdx.x;
    const int w    = tid >> 6, lane = tid & 63;
    const int wr   = w >> 1, wc = w & 1;
    const int quad = lane >> 4, l15 = lane & 15;

    const short* sarr  = (w & 1) ? cn_lo : cn_hi;
    const size_t sbase = ((size_t)b * TLEN + ((w >> 1) ? j : i) * CS) * EDIM;
    const int rr  = lane >> 2;
    const int c16 = (lane & 3) * 8;
    const int csw = c16 ^ (((rr >> 1) & 3) * 8);       // staging swizzle
    const int q8  = (quad ^ ((l15 >> 1) & 3)) * 8;     // frag-read swizzle

    // each wave stages its own tile (w: A_hi / A_lo / B_hi / B_lo), 8x1KB
    auto stage = [&](int ks, int bf) {
        const short* gsrc = sarr + sbase + ks * 32 + csw;
        short* ldst = &tiles[bf][w][0];
#pragma unroll
        for (int t = 0; t < 8; ++t)
            gl_lds16(gsrc + (size_t)(16 * t + rr) * EDIM, ldst + t * 512);
    };

    floatx4 acc[4][4];
#pragma unroll
    for (int rt = 0; rt < 4; ++rt)
#pragma unroll
        for (int ct = 0; ct < 4; ++ct) acc[rt][ct] = (floatx4){0.f, 0.f, 0.f, 0.f};

    stage(0, 0);
    int buf = 0;
    for (int ks = 0; ks < 8; ++ks) {
        if (ks < 7) {
            stage(ks + 1, buf ^ 1);                       // 8 loads in flight
            asm volatile("s_waitcnt vmcnt(8)" ::: "memory");  // old 8 landed
        } else {
            asm volatile("s_waitcnt vmcnt(0)" ::: "memory");
        }
        RAW_BAR();   // all waves' current-buf loads have landed

        short8 bh[4], bl[4];
#pragma unroll
        for (int ct = 0; ct < 4; ++ct) {
            int r = wc * 64 + ct * 16 + l15;
            bh[ct] = *(const short8*)&tiles[buf][2][r * 32 + q8];
            bl[ct] = *(const short8*)&tiles[buf][3][r * 32 + q8];
        }
        __builtin_amdgcn_s_setprio(1);
#pragma unroll
        for (int rt = 0; rt < 4; ++rt) {
            int r = wr * 64 + rt * 16 + l15;
            short8 ah = *(const short8*)&tiles[buf][0][r * 32 + q8];
            short8 al = *(const short8*)&tiles[buf][1][r * 32 + q8];
#pragma unroll
            for (int ct = 0; ct < 4; ++ct) {
                acc[rt][ct] = __builtin_amdgcn_mfma_f32_16x16x32_bf16(ah, bh[ct], acc[rt][ct], 0, 0, 0);
                acc[rt][ct] = __builtin_amdgcn_mfma_f32_16x16x32_bf16(ah, bl[ct], acc[rt][ct], 0, 0, 0);
                acc[rt][ct] = __builtin_amdgcn_mfma_f32_16x16x32_bf16(al, bh[ct], acc[rt][ct], 0, 0, 0);
            }
        }
        __builtin_amdgcn_s_setprio(0);
        RAW_BAR();   // all waves done reading buf before next stage overwrites
        buf ^= 1;
    }

#pragma unroll
    for (int rt = 0; rt < 4; ++rt) {
        float m[4];
#pragma unroll
        for (int reg = 0; reg < 4; ++reg) {
            float mm = acc[rt][0][reg];
#pragma unroll
            for (int ct = 1; ct < 4; ++ct) mm = fmaxf(mm, acc[rt][ct][reg]);
            m[reg] = mm;
        }
#pragma unroll
        for (int off = 1; off < 16; off <<= 1)
#pragma unroll
            for (int reg = 0; reg < 4; ++reg) m[reg] = fmaxf(m[reg], __shfl_xor(m[reg], off));
        if (l15 == 0) {
#pragma unroll
            for (int reg = 0; reg < 4; ++reg)
                redbuf[wc * 128 + wr * 64 + rt * 16 + quad * 4 + reg] = m[reg];
        }
    }
    __syncthreads();

    double part = 0.0;
    if (tid < 128) part = (double)fmaxf(redbuf[tid], redbuf[128 + tid]);
#pragma unroll
    for (int off = 1; off < 64; off <<= 1) part += __shfl_xor(part, off);
    if (lane == 0 && w < 2) red2[w] = part;
    __syncthreads();
    if (tid == 0) scores[(b * NCHUNK + i) * NCHUNK + j] = (float)(red2[0] + red2[1]);
}

// ---------------------------------------------------------------------------
// Stage D v7 (measured best — 199.3 us total in r10; stage-early (r12),
// contiguous layouts (r7), and direct-global B (r4) all null or worse):
// out = dp @ ext + chunk, K=64 steps (2 k32 sub-slices each), 3 LDS buffers,
// prefetch depth 2, ONE raw barrier per step, counted per-wave vmcnt.
// dph = [c][L], xth = [b][e][T]. Verbatim.
// ---------------------------------------------------------------------------
__global__ __launch_bounds__(256) void out_mfma(const float* __restrict__ x,
                                                const short* __restrict__ dph,
                                                const short* __restrict__ xth,
                                                const float* __restrict__ scores,
                                                float* __restrict__ out) {
    __shared__ short As[3][2][128 * 32];   // [buf][sub][c][k]  48 KB
    __shared__ short Bs[3][2][64 * 32];    // [buf][sub][e][k]  24 KB
    __shared__ int   slist[8], sslot[8], snum;
    __shared__ float swei[8];

    const int eq = blockIdx.x, n = blockIdx.y, b = blockIdx.z;
    const int e0 = eq * 64;
    const int tid  = threadIdx.x;
    const int w    = tid >> 6, lane = tid & 63;
    const int wr   = w >> 1, wc = w & 1;
    const int quad = lane >> 4, l15 = lane & 15;
    const int rr   = lane >> 2;
    const int c16  = (lane & 3) * 8;
    const int csw  = c16 ^ (((rr >> 1) & 3) * 8);
    const int q8   = (quad ^ ((l15 >> 1) & 3)) * 8;

    // ---- inlined top-7 (wave 0): candidates j in [0, n) ----
    if (w == 0) {
        const float* srow = scores + (b * NCHUNK + n) * NCHUNK;
        const int nsel = n < KSEL ? n : KSEL;
        float v = (lane < n) ? srow[lane] : -3.0e38f;
        float vals[KSEL];
        int   idxs[KSEL];
        for (int s2 = 0; s2 < nsel; ++s2) {
            float bv = v; int bi = lane;
#pragma unroll
            for (int off = 1; off < 64; off <<= 1) {
                float ov = __shfl_xor(bv, off);
                int   oi = __shfl_xor(bi, off);
                if (ov > bv || (ov == bv && oi < bi)) { bv = ov; bi = oi; }
            }
            vals[s2] = bv; idxs[s2] = bi;
            if (lane == bi) v = -3.0e38f;
        }
        if (lane == 0) {
            float vmin = (nsel > 0) ? vals[nsel - 1] : 0.0f;
            float inv  = 1.0f / (vmin + 1e-6f);
            int shift  = KSEL - nsel;
            int c = 0;
            for (int s2 = 0; s2 < 8; ++s2) {
                int jj; float ww;
                if (s2 < KSEL) {
                    int tt = s2 - shift;
                    if (tt >= 0) { jj = idxs[tt]; ww = vals[tt] * inv; }
                    else         { jj = -1;       ww = 0.0f; }
                } else { jj = n; ww = 1.0f; }
                if (jj >= 0) { slist[c] = jj; sslot[c] = s2; swei[c] = ww; ++c; }
            }
            snum = c;
        }
    }
    __syncthreads();
    const int NT = snum * 2;   // K=64 steps (2 k32 sub-slices per step)

    // stage step st into buffer b3: waves 0-1 stage As (8 loads), 2-3 Bs (4)
    auto stage = [&](int st, int b3) {
        int sv = st >> 1, kh = st & 1;
        if (w < 2) {
#pragma unroll
            for (int sub = 0; sub < 2; ++sub) {
                const short* gsrc = dph + (size_t)(sslot[sv] * 128 + (kh * 2 + sub) * 32) + csw;
#pragma unroll
                for (int t = 0; t < 4; ++t)
                    gl_lds16(gsrc + (size_t)(w * 64 + t * 16 + rr) * LEXT,
                             &As[b3][sub][(w * 64 + t * 16) * 32]);
            }
        } else {
#pragma unroll
            for (int sub = 0; sub < 2; ++sub) {
                const short* gsrc = xth + ((size_t)(b * EDIM + e0)) * TLEN
                                    + (size_t)(slist[sv] * CS + (kh * 2 + sub) * 32) + csw;
#pragma unroll
                for (int t = 0; t < 2; ++t)
                    gl_lds16(gsrc + (size_t)((w - 2) * 32 + t * 16 + rr) * TLEN,
                             &Bs[b3][sub][((w - 2) * 32 + t * 16) * 32]);
            }
        }
    };

    floatx4 accT[4][2], accP[4][2];
#pragma unroll
    for (int rt = 0; rt < 4; ++rt)
#pragma unroll
        for (int ct = 0; ct < 2; ++ct) accT[rt][ct] = (floatx4){0.f, 0.f, 0.f, 0.f};

    stage(0, 0);
    if (NT > 1) stage(1, 1);
    // ensure stage 0 landed (allow stage 1's loads to remain in flight)
    if (w < 2) asm volatile("s_waitcnt vmcnt(8)" ::: "memory");
    else       asm volatile("s_waitcnt vmcnt(4)" ::: "memory");

    int cur = 0;
    for (int st = 0; st < NT; ++st) {
        RAW_BAR();   // all waves: buf 'cur' landed, and compute(st-1) finished

        if ((st & 1) == 0) {
#pragma unroll
            for (int rt = 0; rt < 4; ++rt)
#pragma unroll
                for (int ct = 0; ct < 2; ++ct) accP[rt][ct] = (floatx4){0.f, 0.f, 0.f, 0.f};
        }

#pragma unroll
        for (int sub = 0; sub < 2; ++sub) {
            short8 bh[2];
#pragma unroll
            for (int ct = 0; ct < 2; ++ct) {
                int e = wc * 32 + ct * 16 + l15;
                bh[ct] = *(const short8*)&Bs[cur][sub][e * 32 + q8];
            }
            __builtin_amdgcn_s_setprio(1);
#pragma unroll
            for (int rt = 0; rt < 4; ++rt) {
                int r = wr * 64 + rt * 16 + l15;
                short8 ah = *(const short8*)&As[cur][sub][r * 32 + q8];
#pragma unroll
                for (int ct = 0; ct < 2; ++ct)
                    accP[rt][ct] = __builtin_amdgcn_mfma_f32_16x16x32_bf16(ah, bh[ct], accP[rt][ct], 0, 0, 0);
            }
            __builtin_amdgcn_s_setprio(0);
        }

        if ((st & 1) == 1) {
            float wcur = swei[st >> 1];
#pragma unroll
            for (int rt = 0; rt < 4; ++rt)
#pragma unroll
                for (int ct = 0; ct < 2; ++ct)
#pragma unroll
                    for (int reg = 0; reg < 4; ++reg)
                        accT[rt][ct][reg] += wcur * accP[rt][ct][reg];
        }

        if (st + 2 < NT) {
            int tgt = cur ? cur - 1 : 2;        // (cur+2)%3
            stage(st + 2, tgt);
            if (w < 2) asm volatile("s_waitcnt vmcnt(8)" ::: "memory");
            else       asm volatile("s_waitcnt vmcnt(4)" ::: "memory");
        } else if (st + 1 < NT) {
            asm volatile("s_waitcnt vmcnt(0)" ::: "memory");
        }
        cur = (cur == 2) ? 0 : cur + 1;
    }

#pragma unroll
    for (int rt = 0; rt < 4; ++rt)
#pragma unroll
        for (int ct = 0; ct < 2; ++ct) {
#pragma unroll
            for (int reg = 0; reg < 4; ++reg) {
                int row = wr * 64 + rt * 16 + quad * 4 + reg;
                int col = wc * 32 + ct * 16 + l15;
                size_t o = ((size_t)(b * TLEN + n * CS + row)) * EDIM + e0 + col;
                out[o] = accT[rt][ct][reg] + x[o];
            }
        }
}

// ---------------------------------------------------------------------------
extern "C" void kernel_launch(void* const* d_in, const int* in_sizes, int n_in,
                              void* d_out, int out_size, void* d_ws, size_t ws_size,
                              hipStream_t stream) {
    const float* x  = (const float*)d_in[0];   // [2, 8192, 256] fp32
    const float* dp = (const float*)d_in[1];   // [128, 1024] fp32
    float* out = (float*)d_out;

    char* ws = (char*)d_ws;
    short* cn_hi  = (short*)(ws);                       // 8 MB
    short* cn_lo  = (short*)(ws + (8u << 20));          // 8 MB
    short* xt_hi  = (short*)(ws + (16u << 20));         // 8 MB  [b][e][T]
    short* dp_hi  = (short*)(ws + (24u << 20));         // 256 KB [c][L]
    float* scores = (float*)(ws + (25u << 20));         // 32 KB

    prep_kernel <<<dim3(264), 256, 0, stream>>>(x, dp, cn_hi, cn_lo, xt_hi, dp_hi);
    scores_mfma <<<dim3(NCHUNK * (NCHUNK - 1) / 2, NBATCH), 256, 0, stream>>>(cn_hi, cn_lo, scores);
    out_mfma    <<<dim3(4, NCHUNK, NBATCH), 256, 0, stream>>>(x, dp_hi, xt_hi, scores, out);
}